// Round 4
// baseline (149.037 us; speedup 1.0000x reference)
//
#include <hip/hip_runtime.h>
#include <hip/hip_cooperative_groups.h>
#include <math.h>

namespace cg = cooperative_groups;

#define NT 50      // num event types
#define ND 4       // num decays
#define NB 4       // batch
#define NN 2048    // events per batch
#define TI 32      // events per tile (one block per tile)
#define SUBS 8     // threads per event
#define TILES (NN/TI)          // 64
#define GRID (NB*TILES)        // 256 blocks == 256 CUs, co-resident

__device__ __forceinline__ float softplus_stable(float x) {
    // matches jax.nn.softplus: max(x,0) + log1p(exp(-|x|))
    return fmaxf(x, 0.0f) + log1pf(__expf(-fabsf(x)));
}

// Single cooperative kernel. One block per (batch, 32-event tile).
// Factorization: exp(-w_d(t_i - t_j)) = F_i[d] * E_j[d],
//   F_i[d] = exp(-w_d(t_i - T0)),  E_j[d] = exp(+w_d(t_j - T0)) <= 1  (T0 = tile start)
// Far field (j < tile0) collapses by type: sum_c Ahat[ty_i][c][d] * S[c][d],
//   S[c][d] = sum_{j<tile0, c_j=c} E_j[d]. Intra-tile (<=31 pairs) pairwise.
// Block 0 inits out (zero + baseline compensator) at entry; grid.sync() before the
// final atomics guarantees init-before-accumulate. No workspace, no memset dispatch.
__global__ __launch_bounds__(256) void hawkes_all(
        const float* __restrict__ times,
        const int*   __restrict__ types,
        const float* __restrict__ mask,
        const float* __restrict__ t0v,
        const float* __restrict__ t1v,
        const float* __restrict__ mu_p,
        const float* __restrict__ alpha_p,
        const float* __restrict__ beta_p,
        float* __restrict__ out) {
    __shared__ float4 At4[NT * NT];   // Ahat[ty][c] -> float4 over d ; 40000 B
    __shared__ float4 S4[NT];         // far-field type-binned sums
    __shared__ float4 cls4[NT];       // colsum[c][d] for compensator
    __shared__ float4 E4s[TI];        // intra-tile E factors
    __shared__ int    ctile[TI];      // c_j of intra-tile events
    __shared__ float  wls[4];
    __shared__ float  redA[8];

    int t     = threadIdx.x;
    int b     = blockIdx.x >> 6;          // TILES = 64
    int k     = blockIdx.x & 63;
    int tile0 = k * TI;
    int base  = b * NN;
    int il    = t >> 3;                   // local event 0..31
    int sub   = t & 7;
    int e     = base + tile0 + il;

    if (t < ND) wls[t] = softplus_stable(beta_p[t]);
    if (t < NT) S4[t] = make_float4(0.f, 0.f, 0.f, 0.f);

    // block 0: init out = {0, baseline compensator} before anyone's atomics
    if (blockIdx.x == 0 && t < 64) {
        float sp = (t < NT) ? softplus_stable(mu_p[t]) : 0.f;
        #pragma unroll
        for (int off = 32; off > 0; off >>= 1) sp += __shfl_down(sp, off, 64);
        if (t == 0) {
            #pragma unroll
            for (int bb = 0; bb < NB; ++bb) {
                out[bb]      = 0.f;
                out[NB + bb] = (t1v[bb] - t0v[bb]) * sp;
            }
            __threadfence();
        }
    }
    __syncthreads();
    float w0 = wls[0], w1 = wls[1], w2 = wls[2], w3 = wls[3];
    float T0 = times[base + tile0];

    // stage softplus(alpha) direct [ty][c] layout (far-field read is bank-conflict-free)
    for (int q = t; q < NT * NT; q += 256) {
        float4 a = ((const float4*)alpha_p)[q];     // coalesced, L2-broadcast
        a.x = softplus_stable(a.x); a.y = softplus_stable(a.y);
        a.z = softplus_stable(a.z); a.w = softplus_stable(a.w);
        At4[q] = a;
    }
    // far-field type-binned sums S[c][d] over j < tile0
    for (int j = t; j < tile0; j += 256) {
        float dt = times[base + j] - T0;            // <= 0 -> E <= 1
        int   cj = types[base + j];
        float* sp = (float*)&S4[cj];
        atomicAdd(sp + 0, __expf(w0 * dt));
        atomicAdd(sp + 1, __expf(w1 * dt));
        atomicAdd(sp + 2, __expf(w2 * dt));
        atomicAdd(sp + 3, __expf(w3 * dt));
    }
    // intra-tile E factors
    if (t < TI) {
        int j = tile0 + t;
        float dt = times[base + j] - T0;            // >= 0, small
        E4s[t] = make_float4(__expf(w0 * dt), __expf(w1 * dt),
                             __expf(w2 * dt), __expf(w3 * dt));
        ctile[t] = types[base + j];
    }
    float ti_ = times[e];
    int   ty  = types[e];
    float ddt = ti_ - T0;
    float F0 = __expf(-w0 * ddt), F1 = __expf(-w1 * ddt);
    float F2 = __expf(-w2 * ddt), F3 = __expf(-w3 * ddt);
    __syncthreads();                                // At4/S4/E4s ready

    // colsum[c][d] = sum_ty Ahat[ty][c][d]   (consecutive floats across lanes: no conflict)
    if (t < NT * ND) {
        int c = t >> 2, d = t & 3;
        const float* Af = (const float*)At4;
        float s = 0.f;
        for (int yy = 0; yy < NT; ++yy) s += Af[yy * (NT * 4) + c * 4 + d];
        ((float*)&cls4[c])[d] = s;
    }

    int tyNT = ty * NT;
    float a0 = 0.f, a1 = 0.f, a2 = 0.f, a3 = 0.f;
    if (tile0 > 0) {
        for (int c = sub; c < NT; c += SUBS) {      // far-field dot, split 8 ways
            float4 A = At4[tyNT + c];
            float4 S = S4[c];
            a0 = fmaf(A.x, S.x, a0); a1 = fmaf(A.y, S.y, a1);
            a2 = fmaf(A.z, S.z, a2); a3 = fmaf(A.w, S.w, a3);
        }
    }
    for (int jj = sub; jj < il; jj += SUBS) {       // intra-tile pairs (j < i strict)
        float4 A = At4[tyNT + ctile[jj]];
        float4 E = E4s[jj];
        a0 = fmaf(A.x, E.x, a0); a1 = fmaf(A.y, E.y, a1);
        a2 = fmaf(A.z, E.z, a2); a3 = fmaf(A.w, E.w, a3);
    }
    float p = w0 * F0 * a0 + w1 * F1 * a1 + w2 * F2 * a2 + w3 * F3 * a3;
    p += __shfl_xor(p, 1, 64);
    p += __shfl_xor(p, 2, 64);
    p += __shfl_xor(p, 4, 64);
    __syncthreads();                                // cls4 ready

    // per-event epilogue (sub 0), then block reduction
    float ll = 0.f, cp = 0.f;
    if (sub == 0) {
        float mk   = mask[e];
        float rate = softplus_stable(mu_p[ty]) + p;
        ll = logf(rate + 1e-8f) * mk;
        float tt = t1v[b] - ti_;
        float4 cs = cls4[ty];
        cp = (cs.x * (1.f - __expf(-w0 * tt)) + cs.y * (1.f - __expf(-w1 * tt)) +
              cs.z * (1.f - __expf(-w2 * tt)) + cs.w * (1.f - __expf(-w3 * tt))) * mk;
    }
    #pragma unroll
    for (int off = 8; off < 64; off <<= 1) {
        ll += __shfl_xor(ll, off, 64);
        cp += __shfl_xor(cp, off, 64);
    }
    int lane = t & 63, wid = t >> 6;
    if (lane == 0) { redA[wid] = ll; redA[4 + wid] = cp; }
    __syncthreads();

    float outll = 0.f, outcp = 0.f;
    if (t == 0) {
        outll = redA[0] + redA[1] + redA[2] + redA[3];
        outcp = redA[4] + redA[5] + redA[6] + redA[7];
    }

    cg::this_grid().sync();                         // out init complete grid-wide

    if (t == 0) {
        atomicAdd(&out[b],      outll);
        atomicAdd(&out[NB + b], outcp);
    }
}

extern "C" void kernel_launch(void* const* d_in, const int* in_sizes, int n_in,
                              void* d_out, int out_size, void* d_ws, size_t ws_size,
                              hipStream_t stream) {
    const float* times   = (const float*)d_in[0];
    const int*   types   = (const int*)  d_in[1];
    const float* mask    = (const float*)d_in[2];
    const float* t0      = (const float*)d_in[3];
    const float* t1      = (const float*)d_in[4];
    const float* mu_p    = (const float*)d_in[5];
    const float* alpha_p = (const float*)d_in[6];
    const float* beta_p  = (const float*)d_in[7];
    float* out = (float*)d_out;

    void* args[] = { (void*)&times, (void*)&types, (void*)&mask, (void*)&t0,
                     (void*)&t1, (void*)&mu_p, (void*)&alpha_p, (void*)&beta_p,
                     (void*)&out };
    hipLaunchCooperativeKernel((const void*)hawkes_all, dim3(GRID), dim3(256),
                               args, 0, stream);
}

// Round 5
// 84.371 us; speedup vs baseline: 1.7664x; 1.7664x over previous
//
#include <hip/hip_runtime.h>
#include <math.h>

#define NT 50      // num event types
#define ND 4       // num decays
#define NB 4       // batch
#define NN 2048    // events per batch
#define TI 32      // events per tile (one block per tile)
#define SUBS 8     // threads per event
#define TILES (NN/TI)          // 64
#define GRID (NB*TILES)        // 256 blocks == 256 CUs

__device__ __forceinline__ float softplus_fast(float x) {
    // softplus = max(x,0) + log1p(exp(-|x|)); y=exp(-|x|) in (0,1] so 1+y has no
    // cancellation -> __logf(1+y) matches log1pf to ~1e-7 abs, no libm call.
    return fmaxf(x, 0.0f) + __logf(1.0f + __expf(-fabsf(x)));
}

// ---------------- hawkes: one block per (batch, 32-event tile) ----------------
// Factorization: exp(-w_d(t_i - t_j)) = F_i[d] * E_j[d],
//   F_i[d] = exp(-w_d(t_i - T0)),  E_j[d] = exp(+w_d(t_j - T0)) <= 1  (T0 = tile start)
// Far field (j < tile0) collapses by type: sum_c Ahat[ty_i][c][d] * S[c][d],
//   S[c][d] = sum_{j<tile0, c_j=c} E_j[d]. Intra-tile (<=31 pairs) pairwise.
// Output: per-block {loglik, compensator} partials -> ws (plain stores, no init needed).
__global__ __launch_bounds__(256) void hawkes_kernel(
        const float* __restrict__ times,
        const int*   __restrict__ types,
        const float* __restrict__ mask,
        const float* __restrict__ t1v,
        const float* __restrict__ mu_p,
        const float* __restrict__ alpha_p,
        const float* __restrict__ beta_p,
        float* __restrict__ ws) {
    __shared__ float4 At4[NT * NT];   // Ahat[ty][c] -> float4 over d ; 40000 B
    __shared__ float4 S4[NT];         // far-field type-binned sums
    __shared__ float4 cls4[NT];       // colsum[c][d] for compensator
    __shared__ float4 E4s[TI];        // intra-tile E factors
    __shared__ int    ctile[TI];      // c_j of intra-tile events
    __shared__ float  wls[4];
    __shared__ float  redA[8];

    int t     = threadIdx.x;
    int b     = blockIdx.x >> 6;          // TILES = 64
    int k     = blockIdx.x & 63;
    int tile0 = k * TI;
    int base  = b * NN;
    int il    = t >> 3;                   // local event 0..31
    int sub   = t & 7;
    int e     = base + tile0 + il;

    if (t < ND) wls[t] = softplus_fast(beta_p[t]);
    if (t < NT) S4[t] = make_float4(0.f, 0.f, 0.f, 0.f);
    __syncthreads();
    float w0 = wls[0], w1 = wls[1], w2 = wls[2], w3 = wls[3];
    float T0 = times[base + tile0];

    // stage softplus(alpha), direct [ty][c] layout (far-field read bank-conflict-free)
    for (int q = t; q < NT * NT; q += 256) {
        float4 a = ((const float4*)alpha_p)[q];     // coalesced, L2-broadcast
        a.x = softplus_fast(a.x); a.y = softplus_fast(a.y);
        a.z = softplus_fast(a.z); a.w = softplus_fast(a.w);
        At4[q] = a;
    }
    // far-field type-binned sums S[c][d] over j < tile0
    for (int j = t; j < tile0; j += 256) {
        float dt = times[base + j] - T0;            // <= 0 -> E <= 1
        int   cj = types[base + j];
        float* sp = (float*)&S4[cj];
        atomicAdd(sp + 0, __expf(w0 * dt));
        atomicAdd(sp + 1, __expf(w1 * dt));
        atomicAdd(sp + 2, __expf(w2 * dt));
        atomicAdd(sp + 3, __expf(w3 * dt));
    }
    // intra-tile E factors
    if (t < TI) {
        int j = tile0 + t;
        float dt = times[base + j] - T0;            // >= 0, small
        E4s[t] = make_float4(__expf(w0 * dt), __expf(w1 * dt),
                             __expf(w2 * dt), __expf(w3 * dt));
        ctile[t] = types[base + j];
    }
    float ti_ = times[e];
    int   ty  = types[e];
    float ddt = ti_ - T0;
    float F0 = __expf(-w0 * ddt), F1 = __expf(-w1 * ddt);
    float F2 = __expf(-w2 * ddt), F3 = __expf(-w3 * ddt);
    __syncthreads();                                // At4/S4/E4s ready

    // colsum[c][d] = sum_ty Ahat[ty][c][d]  (consecutive lanes -> conflict-free)
    if (t < NT * ND) {
        int c = t >> 2, d = t & 3;
        const float* Af = (const float*)At4;
        float s = 0.f;
        for (int yy = 0; yy < NT; ++yy) s += Af[yy * (NT * 4) + c * 4 + d];
        ((float*)&cls4[c])[d] = s;
    }

    int tyNT = ty * NT;
    float a0 = 0.f, a1 = 0.f, a2 = 0.f, a3 = 0.f;
    if (tile0 > 0) {
        for (int c = sub; c < NT; c += SUBS) {      // far-field dot, split 8 ways
            float4 A = At4[tyNT + c];
            float4 S = S4[c];
            a0 = fmaf(A.x, S.x, a0); a1 = fmaf(A.y, S.y, a1);
            a2 = fmaf(A.z, S.z, a2); a3 = fmaf(A.w, S.w, a3);
        }
    }
    for (int jj = sub; jj < il; jj += SUBS) {       // intra-tile pairs (j < i strict)
        float4 A = At4[tyNT + ctile[jj]];
        float4 E = E4s[jj];
        a0 = fmaf(A.x, E.x, a0); a1 = fmaf(A.y, E.y, a1);
        a2 = fmaf(A.z, E.z, a2); a3 = fmaf(A.w, E.w, a3);
    }
    float p = w0 * F0 * a0 + w1 * F1 * a1 + w2 * F2 * a2 + w3 * F3 * a3;
    p += __shfl_xor(p, 1, 64);
    p += __shfl_xor(p, 2, 64);
    p += __shfl_xor(p, 4, 64);
    __syncthreads();                                // cls4 ready

    // per-event epilogue (sub 0), then block reduction
    float ll = 0.f, cp = 0.f;
    if (sub == 0) {
        float mk   = mask[e];
        float rate = softplus_fast(mu_p[ty]) + p;
        ll = __logf(rate + 1e-8f) * mk;
        float tt = t1v[b] - ti_;
        float4 cs = cls4[ty];
        cp = (cs.x * (1.f - __expf(-w0 * tt)) + cs.y * (1.f - __expf(-w1 * tt)) +
              cs.z * (1.f - __expf(-w2 * tt)) + cs.w * (1.f - __expf(-w3 * tt))) * mk;
    }
    #pragma unroll
    for (int off = 8; off < 64; off <<= 1) {
        ll += __shfl_xor(ll, off, 64);
        cp += __shfl_xor(cp, off, 64);
    }
    int lane = t & 63, wid = t >> 6;
    if (lane == 0) { redA[wid] = ll; redA[4 + wid] = cp; }
    __syncthreads();
    if (t == 0) {
        ws[blockIdx.x]        = redA[0] + redA[1] + redA[2] + redA[3];
        ws[GRID + blockIdx.x] = redA[4] + redA[5] + redA[6] + redA[7];
    }
}

// ---------------- finalize: 1 block; wave w reduces batch w's 64 partials ----------------
__global__ __launch_bounds__(256) void finalize_kernel(
        const float* __restrict__ t0v,
        const float* __restrict__ t1v,
        const float* __restrict__ mu_p,
        const float* __restrict__ ws,
        float* __restrict__ out) {
    int t    = threadIdx.x;
    int b    = t >> 6;                    // batch = wave id (blocks b*64..b*64+63)
    int lane = t & 63;

    float ll = ws[b * 64 + lane];
    float cp = ws[GRID + b * 64 + lane];
    float sp = (lane < NT) ? softplus_fast(mu_p[lane]) : 0.f;
    #pragma unroll
    for (int off = 32; off > 0; off >>= 1) {
        ll += __shfl_down(ll, off, 64);
        cp += __shfl_down(cp, off, 64);
        sp += __shfl_down(sp, off, 64);
    }
    if (lane == 0) {
        out[b]      = ll;
        out[NB + b] = (t1v[b] - t0v[b]) * sp + cp;
    }
}

extern "C" void kernel_launch(void* const* d_in, const int* in_sizes, int n_in,
                              void* d_out, int out_size, void* d_ws, size_t ws_size,
                              hipStream_t stream) {
    const float* times   = (const float*)d_in[0];
    const int*   types   = (const int*)  d_in[1];
    const float* mask    = (const float*)d_in[2];
    const float* t0      = (const float*)d_in[3];
    const float* t1      = (const float*)d_in[4];
    const float* mu_p    = (const float*)d_in[5];
    const float* alpha_p = (const float*)d_in[6];
    const float* beta_p  = (const float*)d_in[7];
    float* out = (float*)d_out;
    float* ws  = (float*)d_ws;

    hawkes_kernel<<<GRID, 256, 0, stream>>>(times, types, mask, t1,
                                            mu_p, alpha_p, beta_p, ws);
    finalize_kernel<<<1, 256, 0, stream>>>(t0, t1, mu_p, ws, out);
}